// Round 3
// baseline (15425.249 us; speedup 1.0000x reference)
//
#include <hip/hip_runtime.h>
#include <hip/hip_bf16.h>
#include <cstdint>
#include <cstddef>

#define BB   256   // batch
#define SS   512   // encoder seq len
#define RDIM 128   // embed dim
#define HH   512   // hidden
#define TT   96    // decoder steps
#define STRA 1040  // LDS A-stage row stride in f16 (2080B, uint4-aligned)

typedef unsigned int u32;
typedef _Float16 f16;
typedef __attribute__((ext_vector_type(8))) _Float16 f16x8;
typedef __attribute__((ext_vector_type(4))) float f32x4;

__device__ __forceinline__ float sigm(float x){ return 1.0f/(1.0f+__expf(-x)); }
__device__ __forceinline__ float tanh_f(float x){ return 1.0f - 2.0f/(__expf(2.0f*x)+1.0f); }
__device__ __forceinline__ float2 cvt2(u32 x){
  union { u32 u; f16 h[2]; } t; t.u = x;
  return make_float2((float)t.h[0], (float)t.h[1]);
}

// ---------------------------------------------------------------------------
// Prep kernels (once per call)
// ---------------------------------------------------------------------------

// u[n]=Wih[n,:]@embW ; v[n]=Wih[n,:]@embB + bih + bhh ; bd[n]=dec_bih+dec_bhh
__global__ void prep_uv(const float* __restrict__ Wih, const float* __restrict__ embW,
                        const float* __restrict__ embB, const float* __restrict__ bih,
                        const float* __restrict__ bhh, const float* __restrict__ dbih,
                        const float* __restrict__ dbhh,
                        float* __restrict__ u, float* __restrict__ v, float* __restrict__ bd){
  int n = blockIdx.x*256 + threadIdx.x;   // 0..2047
  const float* row = Wih + (size_t)n*RDIM;
  float su = 0.f, sv = 0.f;
  for(int r=0;r<RDIM;r++){ float w = row[r]; su += w*embW[r]; sv += w*embB[r]; }
  u[n] = su;
  v[n] = sv + bih[n] + bhh[n];
  bd[n] = dbih[n] + dbhh[n];
}

// Wqk_t[n][a] = sum_h' Wq[h',a] * Wk[h',n]
__global__ void prep_wqk(const float* __restrict__ Wq, const float* __restrict__ Wk,
                         float* __restrict__ Wqk_t){
  __shared__ float wkc[HH];
  int n = blockIdx.x;
  for(int i=threadIdx.x;i<HH;i+=256) wkc[i] = Wk[(size_t)i*HH + n];
  __syncthreads();
  for(int a=threadIdx.x;a<HH;a+=256){
    float s = 0.f;
    for(int hp=0;hp<HH;hp++) s += Wq[(size_t)hp*HH + a]*wkc[hp];
    Wqk_t[(size_t)n*HH + a] = s;
  }
}

// bqk[n] = sum_h' bq[h'] * Wk[h',n]
__global__ void prep_bqk(const float* __restrict__ bq, const float* __restrict__ Wk,
                         float* __restrict__ bqk){
  int n = blockIdx.x*256 + threadIdx.x;
  float s = 0.f;
  for(int hp=0;hp<HH;hp++) s += bq[hp]*Wk[(size_t)hp*HH + n];
  bqk[n] = s;
}

// Encoder weights fragment-major, 17 kk (16 = Whh, ext kk16 = [u,v,0..]).
// nt = jb*8+ct, ct = gate*2+half: n = gate*512 + jb*32 + half*16 + (L&15)
__global__ void prep_wenc(const float* __restrict__ Whh, const float* __restrict__ u,
                          const float* __restrict__ v, f16* __restrict__ Wfm){
  int nt = blockIdx.x, kk = blockIdx.y, L = threadIdx.x;   // (128,17), 64 thr
  int jb = nt>>3, ct = nt&7;
  int n = (ct>>1)*HH + jb*32 + (ct&1)*16 + (L&15);
  int qq = L>>4;
  union { f16 h[8]; uint4 u4; } z;
  if(kk < 16){
    const float* src = Whh + (size_t)n*HH + kk*32 + qq*8;
    #pragma unroll
    for(int j=0;j<8;j++) z.h[j] = (f16)src[j];
  } else {
    #pragma unroll
    for(int j=0;j<8;j++) z.h[j] = (f16)0.0f;
    if(qq==0){ z.h[0] = (f16)u[n]; z.h[1] = (f16)v[n]; }
  }
  ((uint4*)Wfm)[((size_t)nt*17 + kk)*64 + L] = z.u4;
}

// Decoder weights fragment-major, 32 kk. k<512 -> dWih+dWhh, 512..1023 -> dWih.
__global__ void prep_wdec(const float* __restrict__ dWih, const float* __restrict__ dWhh,
                          f16* __restrict__ Wfm){
  int nt = blockIdx.x, kk = blockIdx.y, L = threadIdx.x;   // (128,32), 64 thr
  int jb = nt>>3, ct = nt&7;
  int n = (ct>>1)*HH + jb*32 + (ct&1)*16 + (L&15);
  int qq = L>>4;
  int k0 = kk*32 + qq*8;
  union { f16 h[8]; uint4 u4; } z;
  #pragma unroll
  for(int j=0;j<8;j++){
    float wv = dWih[(size_t)n*1024 + k0 + j];
    if(k0 + j < HH) wv += dWhh[(size_t)n*HH + k0 + j];
    z.h[j] = (f16)wv;
  }
  ((uint4*)Wfm)[((size_t)nt*32 + kk)*64 + L] = z.u4;
}

// Wqk fragment-major, 16 kk. nt 0..31: n = nt*16 + (L&15)
__global__ void prep_wqfm(const float* __restrict__ Wqk_t, f16* __restrict__ Wfm){
  int nt = blockIdx.x, kk = blockIdx.y, L = threadIdx.x;   // (32,16), 64 thr
  int n = nt*16 + (L&15);
  int qq = L>>4;
  union { f16 h[8]; uint4 u4; } z;
  const float* src = Wqk_t + (size_t)n*HH + kk*32 + qq*8;
  #pragma unroll
  for(int j=0;j<8;j++) z.h[j] = (f16)src[j];
  ((uint4*)Wfm)[((size_t)nt*16 + kk)*64 + L] = z.u4;
}

// ---------------------------------------------------------------------------
// Group barrier: 16 blocks, device-scope atomics, release/acquire.
// All 256 blocks are co-resident (1 block/CU forced by VGPR pressure), so
// spinning is deadlock-free.
// ---------------------------------------------------------------------------
__device__ __forceinline__ void groupbar(u32* slot){
  __syncthreads();
  if(threadIdx.x == 0){
    __hip_atomic_fetch_add(slot, 1u, __ATOMIC_RELEASE, __HIP_MEMORY_SCOPE_AGENT);
    while(__hip_atomic_load(slot, __ATOMIC_ACQUIRE, __HIP_MEMORY_SCOPE_AGENT) < 16u)
      __builtin_amdgcn_s_sleep(1);
  }
  __syncthreads();
}

// ---------------------------------------------------------------------------
// THE persistent kernel. grid 256 = 16 groups x 16 roles; block 256 thr.
// Group gid owns batch rows gid*16..+16 — fully independent of other groups.
// Role owns h-cols role*32..+32 (x4 gates); c state lives in registers for
// the entire 608-step run (enc+dec epilogues share the thread->elem map).
// ---------------------------------------------------------------------------
__global__ void __launch_bounds__(256, 1)
persist(const float* __restrict__ einp, const f16* __restrict__ Wenc,
        const f16* __restrict__ Wdec, const f16* __restrict__ Wqf,
        const float* __restrict__ bd, const float* __restrict__ bqk,
        f16* __restrict__ hb0, f16* __restrict__ hb1, f16* __restrict__ hx,
        f16* __restrict__ ctxg, float* __restrict__ qt,
        const float* __restrict__ outW, const float* __restrict__ outb,
        float* __restrict__ out, u32* __restrict__ bar){
  __shared__ f16 smA[16*STRA];        // 33,280B; aliased as attn xs[32][520]
  __shared__ float gt[128][17];       // gate staging (gc-local x b-local)
  __shared__ float sc[32];

  const int tid = threadIdx.x;
  const int gid = blockIdx.x >> 4;    // batch group
  const int role = blockIdx.x & 15;   // h-col slice
  const int b0 = gid*16;
  const int lane = tid & 63, w = tid >> 6;   // wave 0..3 = gate w
  const int m = lane & 15, q = lane >> 4;
  const int jL = tid & 31, rr = tid >> 5;    // epilogue elems (rr,jL),(rr+8,jL)
  u32* gbar = bar + (size_t)gid*1024;
  f16* hb[2] = {hb0, hb1};

  // encoder B fragments -> registers (gate w, halves 0/1), 17 kk each
  f16x8 Be0[17], Be1[17];
  {
    int nt0 = role*8 + 2*w;
    #pragma unroll
    for(int kk=0;kk<17;kk++){
      Be0[kk] = ((const f16x8*)Wenc)[((size_t)nt0*17 + kk)*64 + lane];
      Be1[kk] = ((const f16x8*)Wenc)[((size_t)(nt0+1)*17 + kk)*64 + lane];
    }
  }
  float c0 = 0.f, c1 = 0.f;    // cell state, resident across all steps

  // ===================== ENCODER (512 steps) =====================
  for(int t=0; t<SS; ++t){
    { // stage h rows b0..b0+15 into smA cols 0..511
      int row = tid>>4, cc = tid&15;
      const uint4* src = (const uint4*)(hb[t&1] + (size_t)(b0+row)*HH);
      uint4* drow = (uint4*)(smA + row*STRA);
      #pragma unroll
      for(int i=0;i<4;i++) drow[cc + 16*i] = src[cc + 16*i];
    }
    if(tid < 64){ // ext chunk cols 512..543: [e, 1, 0...]
      int row = tid>>2, pc = tid&3;
      union { f16 h[8]; uint4 u4; } z;
      #pragma unroll
      for(int j=0;j<8;j++) z.h[j] = (f16)0.0f;
      if(pc==0){ z.h[0] = (f16)einp[(size_t)(b0+row)*SS + t]; z.h[1] = (f16)1.0f; }
      ((uint4*)(smA + row*STRA))[64 + pc] = z.u4;
    }
    __syncthreads();

    f32x4 a0 = {0.f,0.f,0.f,0.f}, a1 = {0.f,0.f,0.f,0.f};
    const f16* arow = smA + m*STRA + q*8;
    #pragma unroll
    for(int kk=0;kk<17;kk++){
      f16x8 a = *(const f16x8*)(arow + kk*32);
      a0 = __builtin_amdgcn_mfma_f32_16x16x32_f16(a, Be0[kk], a0, 0,0,0);
      a1 = __builtin_amdgcn_mfma_f32_16x16x32_f16(a, Be1[kk], a1, 0,0,0);
    }
    #pragma unroll
    for(int r=0;r<4;r++){
      gt[w*32 + m][q*4+r]      = a0[r];   // C/D: col=lane&15, row=q*4+r (b)
      gt[w*32 + 16 + m][q*4+r] = a1[r];
    }
    __syncthreads();

    // epilogue: 2 elems/thread: (rr,jL) and (rr+8,jL)
    #pragma unroll
    for(int qq=0;qq<2;qq++){
      int bl = rr + qq*8;
      float gi = gt[jL][bl];
      float gf = gt[32+jL][bl];
      float gg = gt[64+jL][bl];
      float go = gt[96+jL][bl];
      float& cr = qq ? c1 : c0;
      float cv = sigm(gf)*cr + sigm(gi)*tanh_f(gg);
      cr = cv;
      float hv = sigm(go)*tanh_f(cv);
      int b = b0 + bl, j = role*32 + jL;
      hb[(t+1)&1][(size_t)b*HH + j] = (f16)hv;
      hx[((size_t)b*SS + t)*HH + j] = (f16)hv;
    }
    groupbar(&gbar[t]);
  }

  // ===================== DECODER setup =====================
  f16x8 Bd0[32], Bd1[32];
  {
    int nt0 = role*8 + 2*w;
    #pragma unroll
    for(int kk=0;kk<32;kk++){
      Bd0[kk] = ((const f16x8*)Wdec)[((size_t)nt0*32 + kk)*64 + lane];
      Bd1[kk] = ((const f16x8*)Wdec)[((size_t)(nt0+1)*32 + kk)*64 + lane];
    }
  }
  const float bd0v = bd[w*HH + role*32 + m];
  const float bd1v = bd[w*HH + role*32 + 16 + m];
  const float bqv  = (w < 2) ? bqk[role*32 + w*16 + m] : 0.f;
  const float oW0 = outW[role*32 + jL];          // j for elem (rr,jL)
  const float ob0 = outb[0];
  const int battn = b0 + role;                    // this block's attention row

  // ===================== DECODER (96 steps) =====================
  for(int t=0; t<TT; ++t){
    { // stage h rows for qproj
      int row = tid>>4, cc = tid&15;
      const uint4* src = (const uint4*)(hb[t&1] + (size_t)(b0+row)*HH);
      uint4* drow = (uint4*)(smA + row*STRA);
      #pragma unroll
      for(int i=0;i<4;i++) drow[cc + 16*i] = src[cc + 16*i];
    }
    __syncthreads();
    // qproj: waves 0,1; q[16b x 32qc] per block, B streamed from L2
    if(w < 2){
      f32x4 aq = {0.f,0.f,0.f,0.f};
      int nt = role*2 + w;
      const f16* arow = smA + m*STRA + q*8;
      #pragma unroll
      for(int kk=0;kk<16;kk++){
        f16x8 a = *(const f16x8*)(arow + kk*32);
        f16x8 bf = ((const f16x8*)Wqf)[((size_t)nt*16 + kk)*64 + lane];
        aq = __builtin_amdgcn_mfma_f32_16x16x32_f16(a, bf, aq, 0,0,0);
      }
      #pragma unroll
      for(int r=0;r<4;r++)
        qt[(size_t)(b0 + q*4 + r)*HH + role*32 + w*16 + m] = aq[r] + bqv;
    }
    groupbar(&gbar[SS + t*3]);

    // ---- attention for row battn (flash, online softmax over S=512) ----
    {
      unsigned short* xs = (unsigned short*)smA;   // [32][520] alias
      const int seg = tid & 7, sp = tid >> 3;
      float qreg[64];
      {
        const float4* qv = (const float4*)(qt + (size_t)battn*HH + seg*64);
        #pragma unroll
        for(int i=0;i<16;i++){
          float4 v4 = qv[i];
          qreg[i*4+0]=v4.x; qreg[i*4+1]=v4.y; qreg[i*4+2]=v4.z; qreg[i*4+3]=v4.w;
        }
      }
      float mm = -1e30f, ll = 0.f, aa0 = 0.f, aa1 = 0.f;
      const uint4* src = (const uint4*)(hx + (size_t)battn*SS*HH);
      for(int tile=0; tile<16; ++tile){
        __syncthreads();
        const uint4* tsrc = src + (size_t)tile*2048;
        #pragma unroll
        for(int kk=0;kk<8;kk++){
          uint4 vv = tsrc[kk*256 + tid];
          int e  = (kk*256 + tid)*8;
          int ss = e >> 9, hh = e & 511;
          *(uint4*)&xs[ss*520 + hh] = vv;
        }
        __syncthreads();
        float p = 0.f;
        const uint4* xrow = (const uint4*)&xs[sp*520 + seg*64];
        #pragma unroll
        for(int i=0;i<8;i++){
          uint4 vv = xrow[i];
          float2 t0 = cvt2(vv.x), t1 = cvt2(vv.y), t2 = cvt2(vv.z), t3 = cvt2(vv.w);
          p = fmaf(qreg[i*8+0], t0.x, p);
          p = fmaf(qreg[i*8+1], t0.y, p);
          p = fmaf(qreg[i*8+2], t1.x, p);
          p = fmaf(qreg[i*8+3], t1.y, p);
          p = fmaf(qreg[i*8+4], t2.x, p);
          p = fmaf(qreg[i*8+5], t2.y, p);
          p = fmaf(qreg[i*8+6], t3.x, p);
          p = fmaf(qreg[i*8+7], t3.y, p);
        }
        p += __shfl_xor(p, 1);
        p += __shfl_xor(p, 2);
        p += __shfl_xor(p, 4);
        if(seg == 0) sc[sp] = p;
        __syncthreads();
        float tmax = -1e30f;
        #pragma unroll
        for(int s2=0;s2<32;s2++) tmax = fmaxf(tmax, sc[s2]);
        float mnew  = fmaxf(mm, tmax);
        float alpha = __expf(mm - mnew);
        aa0 *= alpha; aa1 *= alpha; ll *= alpha;
        #pragma unroll 4
        for(int s2=0;s2<32;s2++){
          float pv = __expf(sc[s2] - mnew);
          ll += pv;
          u32 xv = *(const u32*)&xs[s2*520 + 2*tid];
          float2 xf = cvt2(xv);
          aa0 = fmaf(pv, xf.x, aa0);
          aa1 = fmaf(pv, xf.y, aa1);
        }
        mm = mnew;
      }
      float inv = 1.0f/ll;
      union { u32 u; f16 h[2]; } pk;
      pk.h[0] = (f16)(aa0*inv); pk.h[1] = (f16)(aa1*inv);
      *(u32*)(ctxg + (size_t)battn*HH + 2*tid) = pk.u;
    }
    groupbar(&gbar[SS + t*3 + 1]);

    { // stage [h | ctx] rows into smA cols 0..1023
      int row = tid>>4, cc = tid&15;
      const uint4* srch = (const uint4*)(hb[t&1]  + (size_t)(b0+row)*HH);
      const uint4* srcc = (const uint4*)(ctxg     + (size_t)(b0+row)*HH);
      uint4* drow = (uint4*)(smA + row*STRA);
      #pragma unroll
      for(int i=0;i<8;i++){
        int c = cc + 16*i;
        drow[c] = (c < 64) ? srch[c] : srcc[c-64];
      }
    }
    __syncthreads();

    // gates GEMM: K=1024, bias via acc-init
    f32x4 a0 = {bd0v,bd0v,bd0v,bd0v}, a1 = {bd1v,bd1v,bd1v,bd1v};
    {
      const f16* arow = smA + m*STRA + q*8;
      #pragma unroll
      for(int kk=0;kk<32;kk++){
        f16x8 a = *(const f16x8*)(arow + kk*32);
        a0 = __builtin_amdgcn_mfma_f32_16x16x32_f16(a, Bd0[kk], a0, 0,0,0);
        a1 = __builtin_amdgcn_mfma_f32_16x16x32_f16(a, Bd1[kk], a1, 0,0,0);
      }
    }
    #pragma unroll
    for(int r=0;r<4;r++){
      gt[w*32 + m][q*4+r]      = a0[r];
      gt[w*32 + 16 + m][q*4+r] = a1[r];
    }
    __syncthreads();

    float po[2];
    #pragma unroll
    for(int qq=0;qq<2;qq++){
      int bl = rr + qq*8;
      float gi = gt[jL][bl];
      float gf = gt[32+jL][bl];
      float gg = gt[64+jL][bl];
      float go = gt[96+jL][bl];
      float& cr = qq ? c1 : c0;
      float cv = sigm(gf)*cr + sigm(gi)*tanh_f(gg);
      cr = cv;
      float hv = sigm(go)*tanh_f(cv);
      int b = b0 + bl, j = role*32 + jL;
      hb[(t+1)&1][(size_t)b*HH + j] = (f16)hv;
      po[qq] = hv * oW0;
    }
    // reduce partial out over jL (32 contiguous lanes) and atomically add
    #pragma unroll
    for(int k=1;k<32;k<<=1){
      po[0] += __shfl_xor(po[0], k);
      po[1] += __shfl_xor(po[1], k);
    }
    if(jL == 0){
      float bias = (role == 0) ? ob0 : 0.f;
      atomicAdd(&out[(size_t)(b0 + rr)*TT + t],     po[0] + bias);
      atomicAdd(&out[(size_t)(b0 + rr + 8)*TT + t], po[1] + bias);
    }
    groupbar(&gbar[SS + t*3 + 2]);
  }
}

// ---------------------------------------------------------------------------
extern "C" void kernel_launch(void* const* d_in, const int* in_sizes, int n_in,
                              void* d_out, int out_size, void* d_ws, size_t ws_size,
                              hipStream_t stream){
  const float* enc_in = (const float*)d_in[0];
  const float* embW = (const float*)d_in[2];
  const float* embB = (const float*)d_in[3];
  const float* eWih = (const float*)d_in[4];
  const float* eWhh = (const float*)d_in[5];
  const float* ebih = (const float*)d_in[6];
  const float* ebhh = (const float*)d_in[7];
  const float* dWih = (const float*)d_in[8];
  const float* dWhh = (const float*)d_in[9];
  const float* dbih = (const float*)d_in[10];
  const float* dbhh = (const float*)d_in[11];
  const float* Wq   = (const float*)d_in[12];
  const float* bq   = (const float*)d_in[13];
  const float* Wk   = (const float*)d_in[14];
  // d_in[15]: bk — softmax-invariant, unused
  const float* outW = (const float*)d_in[16];
  const float* outb = (const float*)d_in[17];

  // ---- workspace layout (bytes, 16B aligned) ----
  char* base = (char*)d_ws;
  f16* Wenc   = (f16*)(base + 0);            // 128*17*64*16 = 2,228,224
  f16* Wdec   = (f16*)(base + 2228224);      // 128*32*64*16 = 4,194,304
  f16* Wqf    = (f16*)(base + 6422528);      // 32*16*64*16  =   524,288
  f16* hb0    = (f16*)(base + 6946816);      // 262,144
  f16* hb1    = (f16*)(base + 7208960);      // 262,144
  f16* ctxg   = (f16*)(base + 7471104);      // 262,144
  float* qt   = (float*)(base + 7733248);    // 524,288
  float* Wqk_t= (float*)(base + 8257536);    // 1,048,576
  float* u    = (float*)(base + 9306112);    // 8,192
  float* v    = (float*)(base + 9314304);    // 8,192
  float* bd   = (float*)(base + 9322496);    // 8,192
  float* bqk  = (float*)(base + 9330688);    // 2,048
  u32* bar    = (u32*)(base + 9332736);      // 16*1024*4 = 65,536
  f16* hx     = (f16*)(base + 9437184);      // 134,217,728  (ends ~143.6MB)

  hipMemsetAsync(hb0, 0, (size_t)BB*HH*sizeof(f16), stream);
  hipMemsetAsync(bar, 0, 16*1024*sizeof(u32), stream);
  hipMemsetAsync(d_out, 0, (size_t)out_size*sizeof(float), stream);

  prep_uv  <<<8, 256, 0, stream>>>(eWih, embW, embB, ebih, ebhh, dbih, dbhh, u, v, bd);
  prep_bqk <<<2, 256, 0, stream>>>(bq, Wk, bqk);
  prep_wqk <<<512, 256, 0, stream>>>(Wq, Wk, Wqk_t);
  prep_wenc<<<dim3(128,17), 64, 0, stream>>>(eWhh, u, v, Wenc);
  prep_wdec<<<dim3(128,32), 64, 0, stream>>>(dWih, dWhh, Wdec);
  prep_wqfm<<<dim3(32,16),  64, 0, stream>>>(Wqk_t, Wqf);

  persist<<<256, 256, 0, stream>>>(enc_in, Wenc, Wdec, Wqf, bd, bqk,
                                   hb0, hb1, hx, ctxg, qt,
                                   outW, outb, (float*)d_out, bar);
}

// Round 4
// 12395.551 us; speedup vs baseline: 1.2444x; 1.2444x over previous
//
#include <hip/hip_runtime.h>
#include <hip/hip_bf16.h>
#include <cstdint>
#include <cstddef>

#define BB   256   // batch
#define SS   512   // encoder seq len
#define RDIM 128   // embed dim
#define HH   512   // hidden
#define TT   96    // decoder steps
#define STRA 1048  // LDS A-stage row stride in f16 (2096B)

typedef unsigned int u32;
typedef unsigned long long u64;
typedef _Float16 f16;
typedef __attribute__((ext_vector_type(8))) _Float16 f16x8;
typedef __attribute__((ext_vector_type(4))) float f32x4;

__device__ __forceinline__ float sigm(float x){ return 1.0f/(1.0f+__expf(-x)); }
__device__ __forceinline__ float tanh_f(float x){ return 1.0f - 2.0f/(__expf(2.0f*x)+1.0f); }
__device__ __forceinline__ float2 cvt2(u32 x){
  union { u32 u; f16 h[2]; } t; t.u = x;
  return make_float2((float)t.h[0], (float)t.h[1]);
}

// Relaxed agent-scope (sc1) data movement: per-access coherent at MALL,
// no buffer_wbl2/buffer_inv cache flushes (those come only with acq/rel).
__device__ __forceinline__ u64 xld(const u64* p){
  return __hip_atomic_load(p, __ATOMIC_RELAXED, __HIP_MEMORY_SCOPE_AGENT);
}
__device__ __forceinline__ void xst(u32* p, u32 v){
  __hip_atomic_store(p, v, __ATOMIC_RELAXED, __HIP_MEMORY_SCOPE_AGENT);
}

// ---------------------------------------------------------------------------
// Prep kernels
// ---------------------------------------------------------------------------
__global__ void prep_uv(const float* __restrict__ Wih, const float* __restrict__ embW,
                        const float* __restrict__ embB, const float* __restrict__ bih,
                        const float* __restrict__ bhh, const float* __restrict__ dbih,
                        const float* __restrict__ dbhh,
                        float* __restrict__ u, float* __restrict__ v, float* __restrict__ bd){
  int n = blockIdx.x*256 + threadIdx.x;   // 0..2047
  const float* row = Wih + (size_t)n*RDIM;
  float su = 0.f, sv = 0.f;
  for(int r=0;r<RDIM;r++){ float w = row[r]; su += w*embW[r]; sv += w*embB[r]; }
  u[n] = su;
  v[n] = sv + bih[n] + bhh[n];
  bd[n] = dbih[n] + dbhh[n];
}

__global__ void prep_wqk(const float* __restrict__ Wq, const float* __restrict__ Wk,
                         float* __restrict__ Wqk_t){
  __shared__ float wkc[HH];
  int n = blockIdx.x;
  for(int i=threadIdx.x;i<HH;i+=256) wkc[i] = Wk[(size_t)i*HH + n];
  __syncthreads();
  for(int a=threadIdx.x;a<HH;a+=256){
    float s = 0.f;
    for(int hp=0;hp<HH;hp++) s += Wq[(size_t)hp*HH + a]*wkc[hp];
    Wqk_t[(size_t)n*HH + a] = s;
  }
}

__global__ void prep_bqk(const float* __restrict__ bq, const float* __restrict__ Wk,
                         float* __restrict__ bqk){
  int n = blockIdx.x*256 + threadIdx.x;
  float s = 0.f;
  for(int hp=0;hp<HH;hp++) s += bq[hp]*Wk[(size_t)hp*HH + n];
  bqk[n] = s;
}

// Encoder weights frag-major. nt = gate*32 + role: n = gate*512 + role*16 + (L&15).
// kk<16: Whh; kk==16 ext: [u, v, 0...]
__global__ void prep_wenc(const float* __restrict__ Whh, const float* __restrict__ u,
                          const float* __restrict__ v, f16* __restrict__ Wfm){
  int nt = blockIdx.x, kk = blockIdx.y, L = threadIdx.x;   // (128,17), 64 thr
  int n = (nt>>5)*HH + (nt&31)*16 + (L&15);
  int qq = L>>4;
  union { f16 h[8]; uint4 u4; } z;
  if(kk < 16){
    const float* src = Whh + (size_t)n*HH + kk*32 + qq*8;
    #pragma unroll
    for(int j=0;j<8;j++) z.h[j] = (f16)src[j];
  } else {
    #pragma unroll
    for(int j=0;j<8;j++) z.h[j] = (f16)0.0f;
    if(qq==0){ z.h[0] = (f16)u[n]; z.h[1] = (f16)v[n]; }
  }
  ((uint4*)Wfm)[((size_t)nt*17 + kk)*64 + L] = z.u4;
}

// Decoder weights frag-major, 32 kk. k<512 -> dWih+dWhh, else dWih. Bias via acc init.
__global__ void prep_wdec(const float* __restrict__ dWih, const float* __restrict__ dWhh,
                          f16* __restrict__ Wfm){
  int nt = blockIdx.x, kk = blockIdx.y, L = threadIdx.x;   // (128,32), 64 thr
  int n = (nt>>5)*HH + (nt&31)*16 + (L&15);
  int qq = L>>4;
  int k0 = kk*32 + qq*8;
  union { f16 h[8]; uint4 u4; } z;
  #pragma unroll
  for(int j=0;j<8;j++){
    float wv = dWih[(size_t)n*1024 + k0 + j];
    if(k0 + j < HH) wv += dWhh[(size_t)n*HH + k0 + j];
    z.h[j] = (f16)wv;
  }
  ((uint4*)Wfm)[((size_t)nt*32 + kk)*64 + L] = z.u4;
}

// Wqk frag-major: nt 0..31 (n = nt*16 + (L&15)), 16 kk.
__global__ void prep_wqfm(const float* __restrict__ Wqk_t, f16* __restrict__ Wfm){
  int nt = blockIdx.x, kk = blockIdx.y, L = threadIdx.x;   // (32,16), 64 thr
  int n = nt*16 + (L&15);
  int qq = L>>4;
  union { f16 h[8]; uint4 u4; } z;
  const float* src = Wqk_t + (size_t)n*HH + kk*32 + qq*8;
  #pragma unroll
  for(int j=0;j<8;j++) z.h[j] = (f16)src[j];
  ((uint4*)Wfm)[((size_t)nt*16 + kk)*64 + L] = z.u4;
}

// ---------------------------------------------------------------------------
// Fence-free group barrier: __syncthreads drains each wave's vmem (data sc1
// stores hit MALL); tid0 does relaxed agent add + relaxed poll. No L2 flush.
// All 256 blocks co-resident (grid == CU count, 1-2 blocks/CU capacity).
// ---------------------------------------------------------------------------
__device__ __forceinline__ void groupbar(u32* slot){
  __syncthreads();
  if(threadIdx.x == 0){
    __builtin_amdgcn_s_waitcnt(0);
    __hip_atomic_fetch_add(slot, 1u, __ATOMIC_RELAXED, __HIP_MEMORY_SCOPE_AGENT);
    while(__hip_atomic_load(slot, __ATOMIC_RELAXED, __HIP_MEMORY_SCOPE_AGENT) < 32u)
      __builtin_amdgcn_s_sleep(1);
  }
  __syncthreads();
}

// ---------------------------------------------------------------------------
// Persistent kernel: grid 256 = 8 groups (32 batch rows) x 32 roles (16 h-cols).
// c-state in registers for all 608 steps; enc/dec epilogues share thread map.
// hx row (b0+role) is block-PRIVATE (written from staged full-h, read only by
// owner) -> attention scans stay on the cached path.
// ---------------------------------------------------------------------------
__global__ void __launch_bounds__(256, 1)
persist(const float* __restrict__ einp, const f16* __restrict__ Wenc,
        const f16* __restrict__ Wdec, const f16* __restrict__ Wqf,
        const float* __restrict__ bd, const float* __restrict__ bqk,
        f16* __restrict__ hb0, f16* __restrict__ hb1, f16* __restrict__ hx,
        f16* __restrict__ ctxg, float* __restrict__ qtx,
        const float* __restrict__ outW, const float* __restrict__ outb,
        float* __restrict__ out, u32* __restrict__ bar){
  __shared__ f16 smA[32*STRA];                 // 67,072B; aliased as attn xs[32][520]
  __shared__ float gt[64][33];                 // 8,448B gate staging
  __shared__ __align__(16) float qsh[512];     // q row staging for attention
  __shared__ float sc[32];

  const int tid = threadIdx.x;
  const int gid = blockIdx.x >> 5;     // 8 groups
  const int role = blockIdx.x & 31;    // 32 roles
  const int b0 = gid*32;
  const int lane = tid & 63, w = tid >> 6;     // wave = gate
  const int m = lane & 15, q = lane >> 4;
  const int jL2 = (tid & 7)*2, rr = tid >> 3;  // epilogue: (rr, jL2), (rr, jL2+1)
  const int battn = b0 + role;
  u32* gbar = bar + (size_t)gid*1024;
  f16* hb[2] = {hb0, hb1};

  // encoder B frags (68 VGPR)
  f16x8 Be[17];
  {
    const f16x8* wp = (const f16x8*)Wenc + ((size_t)(w*32+role)*17)*64 + lane;
    #pragma unroll
    for(int kk=0;kk<17;kk++) Be[kk] = wp[kk*64];
  }
  float c0 = 0.f, c1 = 0.f;

  // ===================== ENCODER (512 steps) =====================
  for(int t=0; t<SS; ++t){
    { // stage h(t): 32 rows x 512 f16 via sc1 8B loads (cross-block data)
      const u64* src = (const u64*)hb[t&1] + (size_t)b0*128;
      #pragma unroll
      for(int i=0;i<16;i++){
        int e = tid + i*256;
        int row = e >> 7, cq = e & 127;
        u64 v = xld(src + e);
        *(u64*)(smA + row*STRA + cq*4) = v;
      }
    }
    if(tid < 128){ // ext cols 512..543: [e, 1, 0...]
      int row = tid>>2, pc = tid&3;
      union { f16 h[8]; uint4 u4; } z;
      #pragma unroll
      for(int j=0;j<8;j++) z.h[j] = (f16)0.0f;
      if(pc==0){ z.h[0] = (f16)einp[(size_t)(b0+row)*SS + t]; z.h[1] = (f16)1.0f; }
      ((uint4*)(smA + row*STRA))[64 + pc] = z.u4;
    }
    __syncthreads();

    // write private hx row (h output of step t-1) from staged full-h
    if(t > 0 && tid < 64){
      ((uint4*)(hx + ((size_t)battn*SS + (t-1))*HH))[tid] =
          ((const uint4*)(smA + role*STRA))[tid];
    }

    f32x4 a0 = {0.f,0.f,0.f,0.f}, a1 = {0.f,0.f,0.f,0.f};
    const f16* ar0 = smA + m*STRA + q*8;
    const f16* ar1 = smA + (16+m)*STRA + q*8;
    #pragma unroll
    for(int kk=0;kk<17;kk++){
      f16x8 x0 = *(const f16x8*)(ar0 + kk*32);
      f16x8 x1 = *(const f16x8*)(ar1 + kk*32);
      a0 = __builtin_amdgcn_mfma_f32_16x16x32_f16(x0, Be[kk], a0, 0,0,0);
      a1 = __builtin_amdgcn_mfma_f32_16x16x32_f16(x1, Be[kk], a1, 0,0,0);
    }
    #pragma unroll
    for(int r=0;r<4;r++){
      gt[w*16+m][q*4+r]    = a0[r];   // C/D: col=lane&15, row=q*4+r
      gt[w*16+m][16+q*4+r] = a1[r];
    }
    __syncthreads();

    { // epilogue: thread owns (rr, jL2),(rr, jL2+1)
      float gi0=gt[jL2][rr],    gi1=gt[jL2+1][rr];
      float gf0=gt[16+jL2][rr], gf1=gt[17+jL2][rr];
      float gg0=gt[32+jL2][rr], gg1=gt[33+jL2][rr];
      float go0=gt[48+jL2][rr], go1=gt[49+jL2][rr];
      float cv0 = sigm(gf0)*c0 + sigm(gi0)*tanh_f(gg0); c0 = cv0;
      float cv1 = sigm(gf1)*c1 + sigm(gi1)*tanh_f(gg1); c1 = cv1;
      float hv0 = sigm(go0)*tanh_f(cv0);
      float hv1 = sigm(go1)*tanh_f(cv1);
      union { u32 u; f16 h[2]; } pk;
      pk.h[0] = (f16)hv0; pk.h[1] = (f16)hv1;
      xst((u32*)(hb[(t+1)&1] + (size_t)(b0+rr)*HH + role*16 + jL2), pk.u);
    }
    groupbar(&gbar[t]);
  }

  // final hx row (h output of step 511) — final h lives in hb[0]
  if(tid < 128){
    u64 v = xld((const u64*)hb[0] + (size_t)battn*128 + tid);
    ((u64*)(hx + ((size_t)battn*SS + (SS-1))*HH))[tid] = v;
  }

  // decoder B frags (128 VGPR) + scalars
  f16x8 Bd[32];
  {
    const f16x8* wp = (const f16x8*)Wdec + ((size_t)(w*32+role)*32)*64 + lane;
    #pragma unroll
    for(int kk=0;kk<32;kk++) Bd[kk] = wp[kk*64];
  }
  const float bdv = bd[w*HH + role*16 + m];
  const float bqv = (w < 2) ? bqk[role*16 + m] : 0.f;
  const float ow0 = outW[role*16 + jL2];
  const float ow1 = outW[role*16 + jL2 + 1];
  const float ob0 = outb[0];

  // ===================== DECODER (96 steps) =====================
  for(int t=0; t<TT; ++t){
    { // ph1: stage h(t), qproj col-slice (waves 0,1)
      const u64* src = (const u64*)hb[t&1] + (size_t)b0*128;
      #pragma unroll
      for(int i=0;i<16;i++){
        int e = tid + i*256;
        int row = e >> 7, cq = e & 127;
        u64 v = xld(src + e);
        *(u64*)(smA + row*STRA + cq*4) = v;
      }
    }
    __syncthreads();
    if(w < 2){
      f32x4 aq = {0.f,0.f,0.f,0.f};
      const f16* ar = smA + (w*16+m)*STRA + q*8;
      const f16x8* wq = (const f16x8*)Wqf + ((size_t)role*16)*64 + lane;
      #pragma unroll
      for(int kk=0;kk<16;kk++){
        f16x8 x = *(const f16x8*)(ar + kk*32);
        aq = __builtin_amdgcn_mfma_f32_16x16x32_f16(x, wq[kk*64], aq, 0,0,0);
      }
      #pragma unroll
      for(int r=0;r<4;r++){
        float vv = aq[r] + bqv;
        xst((u32*)(qtx + (size_t)(b0 + w*16 + q*4 + r)*HH + role*16 + m),
            __float_as_uint(vv));
      }
    }
    groupbar(&gbar[SS + t*3]);

    { // ph2: attention for private row battn (flash, online softmax)
      ((u64*)qsh)[tid] = xld((const u64*)(qtx + (size_t)battn*HH) + tid);
      __syncthreads();
      const int seg = tid & 7, sp = tid >> 3;
      float qreg[64];
      {
        const float4* qv = (const float4*)(qsh + seg*64);
        #pragma unroll
        for(int i=0;i<16;i++){
          float4 v4 = qv[i];
          qreg[i*4+0]=v4.x; qreg[i*4+1]=v4.y; qreg[i*4+2]=v4.z; qreg[i*4+3]=v4.w;
        }
      }
      unsigned short* xs = (unsigned short*)smA;
      float mm = -1e30f, ll = 0.f, aa0 = 0.f, aa1 = 0.f;
      const uint4* src = (const uint4*)(hx + (size_t)battn*SS*HH);
      for(int tile=0; tile<16; ++tile){
        __syncthreads();
        const uint4* tsrc = src + (size_t)tile*2048;
        #pragma unroll
        for(int kk=0;kk<8;kk++){
          uint4 vv = tsrc[kk*256 + tid];
          int e = (kk*256 + tid)*8;
          int s2 = e >> 9, h2 = e & 511;
          *(uint4*)&xs[s2*520 + h2] = vv;
        }
        __syncthreads();
        float p = 0.f;
        const uint4* xrow = (const uint4*)&xs[sp*520 + seg*64];
        #pragma unroll
        for(int i=0;i<8;i++){
          uint4 vv = xrow[i];
          float2 t0 = cvt2(vv.x), t1 = cvt2(vv.y), t2 = cvt2(vv.z), t3 = cvt2(vv.w);
          p = fmaf(qreg[i*8+0], t0.x, p);
          p = fmaf(qreg[i*8+1], t0.y, p);
          p = fmaf(qreg[i*8+2], t1.x, p);
          p = fmaf(qreg[i*8+3], t1.y, p);
          p = fmaf(qreg[i*8+4], t2.x, p);
          p = fmaf(qreg[i*8+5], t2.y, p);
          p = fmaf(qreg[i*8+6], t3.x, p);
          p = fmaf(qreg[i*8+7], t3.y, p);
        }
        p += __shfl_xor(p, 1);
        p += __shfl_xor(p, 2);
        p += __shfl_xor(p, 4);
        if(seg == 0) sc[sp] = p;
        __syncthreads();
        float tmax = -1e30f;
        #pragma unroll
        for(int s2=0;s2<32;s2++) tmax = fmaxf(tmax, sc[s2]);
        float mnew  = fmaxf(mm, tmax);
        float alpha = __expf(mm - mnew);
        aa0 *= alpha; aa1 *= alpha; ll *= alpha;
        #pragma unroll 4
        for(int s2=0;s2<32;s2++){
          float pv = __expf(sc[s2] - mnew);
          ll += pv;
          u32 xv = *(const u32*)&xs[s2*520 + 2*tid];
          float2 xf = cvt2(xv);
          aa0 = fmaf(pv, xf.x, aa0);
          aa1 = fmaf(pv, xf.y, aa1);
        }
        mm = mnew;
      }
      float inv = 1.0f/ll;
      union { u32 u; f16 h[2]; } pk;
      pk.h[0] = (f16)(aa0*inv); pk.h[1] = (f16)(aa1*inv);
      xst((u32*)(ctxg + (size_t)battn*HH + 2*tid), pk.u);
    }
    groupbar(&gbar[SS + t*3 + 1]);

    { // ph3: stage [h | ctx] (1024 cols) via sc1, gates GEMM, epilogue
      const u64* hsrc = (const u64*)hb[t&1] + (size_t)b0*128;
      const u64* csrc = (const u64*)ctxg    + (size_t)b0*128;
      #pragma unroll
      for(int i=0;i<32;i++){
        int e = tid + i*256;
        int row = e >> 8, cq = e & 255;
        const u64* sp2 = (cq < 128) ? (hsrc + (size_t)row*128 + cq)
                                    : (csrc + (size_t)row*128 + (cq-128));
        u64 v = xld(sp2);
        *(u64*)(smA + row*STRA + cq*4) = v;
      }
    }
    __syncthreads();

    f32x4 a0 = {bdv,bdv,bdv,bdv}, a1 = {bdv,bdv,bdv,bdv};
    {
      const f16* ar0 = smA + m*STRA + q*8;
      const f16* ar1 = smA + (16+m)*STRA + q*8;
      #pragma unroll
      for(int kk=0;kk<32;kk++){
        f16x8 x0 = *(const f16x8*)(ar0 + kk*32);
        f16x8 x1 = *(const f16x8*)(ar1 + kk*32);
        a0 = __builtin_amdgcn_mfma_f32_16x16x32_f16(x0, Bd[kk], a0, 0,0,0);
        a1 = __builtin_amdgcn_mfma_f32_16x16x32_f16(x1, Bd[kk], a1, 0,0,0);
      }
    }
    #pragma unroll
    for(int r=0;r<4;r++){
      gt[w*16+m][q*4+r]    = a0[r];
      gt[w*16+m][16+q*4+r] = a1[r];
    }
    __syncthreads();

    {
      float gi0=gt[jL2][rr],    gi1=gt[jL2+1][rr];
      float gf0=gt[16+jL2][rr], gf1=gt[17+jL2][rr];
      float gg0=gt[32+jL2][rr], gg1=gt[33+jL2][rr];
      float go0=gt[48+jL2][rr], go1=gt[49+jL2][rr];
      float cv0 = sigm(gf0)*c0 + sigm(gi0)*tanh_f(gg0); c0 = cv0;
      float cv1 = sigm(gf1)*c1 + sigm(gi1)*tanh_f(gg1); c1 = cv1;
      float hv0 = sigm(go0)*tanh_f(cv0);
      float hv1 = sigm(go1)*tanh_f(cv1);
      union { u32 u; f16 h[2]; } pk;
      pk.h[0] = (f16)hv0; pk.h[1] = (f16)hv1;
      xst((u32*)(hb[(t+1)&1] + (size_t)(b0+rr)*HH + role*16 + jL2), pk.u);
      float po = hv0*ow0 + hv1*ow1;
      po += __shfl_xor(po, 1);
      po += __shfl_xor(po, 2);
      po += __shfl_xor(po, 4);
      if((tid & 7) == 0){
        float bias = (role == 0) ? ob0 : 0.f;
        atomicAdd(&out[(size_t)(b0+rr)*TT + t], po + bias);
      }
    }
    groupbar(&gbar[SS + t*3 + 2]);
  }
}

// ---------------------------------------------------------------------------
extern "C" void kernel_launch(void* const* d_in, const int* in_sizes, int n_in,
                              void* d_out, int out_size, void* d_ws, size_t ws_size,
                              hipStream_t stream){
  const float* enc_in = (const float*)d_in[0];
  const float* embW = (const float*)d_in[2];
  const float* embB = (const float*)d_in[3];
  const float* eWih = (const float*)d_in[4];
  const float* eWhh = (const float*)d_in[5];
  const float* ebih = (const float*)d_in[6];
  const float* ebhh = (const float*)d_in[7];
  const float* dWih = (const float*)d_in[8];
  const float* dWhh = (const float*)d_in[9];
  const float* dbih = (const float*)d_in[10];
  const float* dbhh = (const float*)d_in[11];
  const float* Wq   = (const float*)d_in[12];
  const float* bq   = (const float*)d_in[13];
  const float* Wk   = (const float*)d_in[14];
  // d_in[15]: bk — softmax-invariant, unused
  const float* outW = (const float*)d_in[16];
  const float* outb = (const float*)d_in[17];

  // ---- workspace layout (bytes, 16B aligned) ----
  char* base = (char*)d_ws;
  f16* Wenc   = (f16*)(base + 0);            // 2,228,224
  f16* Wdec   = (f16*)(base + 2228224);      // 4,194,304
  f16* Wqf    = (f16*)(base + 6422528);      //   524,288
  f16* hb0    = (f16*)(base + 6946816);      //   262,144
  f16* hb1    = (f16*)(base + 7208960);      //   262,144
  f16* ctxg   = (f16*)(base + 7471104);      //   262,144
  float* qtx  = (float*)(base + 7733248);    //   524,288
  float* Wqk_t= (float*)(base + 8257536);    // 1,048,576
  float* u    = (float*)(base + 9306112);    //     8,192
  float* v    = (float*)(base + 9314304);    //     8,192
  float* bd   = (float*)(base + 9322496);    //     8,192
  float* bqk  = (float*)(base + 9330688);    //     2,048
  u32* bar    = (u32*)(base + 9332736);      //    32,768 (8 groups x 1024 slots)
  f16* hx     = (f16*)(base + 9437184);      // 134,217,728

  hipMemsetAsync(hb0, 0, (size_t)BB*HH*sizeof(f16), stream);
  hipMemsetAsync(bar, 0, 8*1024*sizeof(u32), stream);
  hipMemsetAsync(d_out, 0, (size_t)out_size*sizeof(float), stream);

  prep_uv  <<<8, 256, 0, stream>>>(eWih, embW, embB, ebih, ebhh, dbih, dbhh, u, v, bd);
  prep_bqk <<<2, 256, 0, stream>>>(bq, Wk, bqk);
  prep_wqk <<<512, 256, 0, stream>>>(Wq, Wk, Wqk_t);
  prep_wenc<<<dim3(128,17), 64, 0, stream>>>(eWhh, u, v, Wenc);
  prep_wdec<<<dim3(128,32), 64, 0, stream>>>(dWih, dWhh, Wdec);
  prep_wqfm<<<dim3(32,16),  64, 0, stream>>>(Wqk_t, Wqf);

  persist<<<256, 256, 0, stream>>>(enc_in, Wenc, Wdec, Wqf, bd, bqk,
                                   hb0, hb1, hx, ctxg, qtx,
                                   outW, outb, (float*)d_out, bar);
}

// Round 5
// 10227.262 us; speedup vs baseline: 1.5082x; 1.2120x over previous
//
#include <hip/hip_runtime.h>
#include <hip/hip_bf16.h>
#include <cstdint>
#include <cstddef>

#define BB   256   // batch
#define SS   512   // encoder seq len
#define RDIM 128   // embed dim
#define HH   512   // hidden
#define TT   96    // decoder steps
#define STRD 1040  // LDS stage row stride in f16 (2080 B)

typedef unsigned int u32;
typedef unsigned long long u64;
typedef _Float16 f16;
typedef __attribute__((ext_vector_type(8))) _Float16 f16x8;
typedef __attribute__((ext_vector_type(4))) float f32x4;

__device__ __forceinline__ float sigm(float x){ return 1.0f/(1.0f+__expf(-x)); }
__device__ __forceinline__ float tanh_f(float x){ return 1.0f - 2.0f/(__expf(2.0f*x)+1.0f); }
__device__ __forceinline__ float2 cvt2(u32 x){
  union { u32 u; f16 h[2]; } t; t.u = x;
  return make_float2((float)t.h[0], (float)t.h[1]);
}
// relaxed agent-scope (bypass L1/L2, served at MALL; no cache flushes)
__device__ __forceinline__ u64 xld(const u64* p){
  return __hip_atomic_load(p, __ATOMIC_RELAXED, __HIP_MEMORY_SCOPE_AGENT);
}
__device__ __forceinline__ void xst(u32* p, u32 v){
  __hip_atomic_store(p, v, __ATOMIC_RELAXED, __HIP_MEMORY_SCOPE_AGENT);
}

// ---------------------------------------------------------------------------
// Prep kernels (unchanged mappings from R4)
// ---------------------------------------------------------------------------
__global__ void prep_uv(const float* __restrict__ Wih, const float* __restrict__ embW,
                        const float* __restrict__ embB, const float* __restrict__ bih,
                        const float* __restrict__ bhh, const float* __restrict__ dbih,
                        const float* __restrict__ dbhh,
                        float* __restrict__ u, float* __restrict__ v, float* __restrict__ bd){
  int n = blockIdx.x*256 + threadIdx.x;
  const float* row = Wih + (size_t)n*RDIM;
  float su = 0.f, sv = 0.f;
  for(int r=0;r<RDIM;r++){ float w = row[r]; su += w*embW[r]; sv += w*embB[r]; }
  u[n] = su;
  v[n] = sv + bih[n] + bhh[n];
  bd[n] = dbih[n] + dbhh[n];
}

__global__ void prep_wqk(const float* __restrict__ Wq, const float* __restrict__ Wk,
                         float* __restrict__ Wqk_t){
  __shared__ float wkc[HH];
  int n = blockIdx.x;
  for(int i=threadIdx.x;i<HH;i+=256) wkc[i] = Wk[(size_t)i*HH + n];
  __syncthreads();
  for(int a=threadIdx.x;a<HH;a+=256){
    float s = 0.f;
    for(int hp=0;hp<HH;hp++) s += Wq[(size_t)hp*HH + a]*wkc[hp];
    Wqk_t[(size_t)n*HH + a] = s;
  }
}

__global__ void prep_bqk(const float* __restrict__ bq, const float* __restrict__ Wk,
                         float* __restrict__ bqk){
  int n = blockIdx.x*256 + threadIdx.x;
  float s = 0.f;
  for(int hp=0;hp<HH;hp++) s += bq[hp]*Wk[(size_t)hp*HH + n];
  bqk[n] = s;
}

// nt = gate*32 + role: n = gate*512 + role*16 + (L&15); kk16 ext = [u,v,0..]
__global__ void prep_wenc(const float* __restrict__ Whh, const float* __restrict__ u,
                          const float* __restrict__ v, f16* __restrict__ Wfm){
  int nt = blockIdx.x, kk = blockIdx.y, L = threadIdx.x;   // (128,17), 64 thr
  int n = (nt>>5)*HH + (nt&31)*16 + (L&15);
  int qq = L>>4;
  union { f16 h[8]; uint4 u4; } z;
  if(kk < 16){
    const float* src = Whh + (size_t)n*HH + kk*32 + qq*8;
    #pragma unroll
    for(int j=0;j<8;j++) z.h[j] = (f16)src[j];
  } else {
    #pragma unroll
    for(int j=0;j<8;j++) z.h[j] = (f16)0.0f;
    if(qq==0){ z.h[0] = (f16)u[n]; z.h[1] = (f16)v[n]; }
  }
  ((uint4*)Wfm)[((size_t)nt*17 + kk)*64 + L] = z.u4;
}

__global__ void prep_wdec(const float* __restrict__ dWih, const float* __restrict__ dWhh,
                          f16* __restrict__ Wfm){
  int nt = blockIdx.x, kk = blockIdx.y, L = threadIdx.x;   // (128,32), 64 thr
  int n = (nt>>5)*HH + (nt&31)*16 + (L&15);
  int qq = L>>4;
  int k0 = kk*32 + qq*8;
  union { f16 h[8]; uint4 u4; } z;
  #pragma unroll
  for(int j=0;j<8;j++){
    float wv = dWih[(size_t)n*1024 + k0 + j];
    if(k0 + j < HH) wv += dWhh[(size_t)n*HH + k0 + j];
    z.h[j] = (f16)wv;
  }
  ((uint4*)Wfm)[((size_t)nt*32 + kk)*64 + L] = z.u4;
}

__global__ void prep_wqfm(const float* __restrict__ Wqk_t, f16* __restrict__ Wfm){
  int nt = blockIdx.x, kk = blockIdx.y, L = threadIdx.x;   // (32,16), 64 thr
  int n = nt*16 + (L&15);
  int qq = L>>4;
  union { f16 h[8]; uint4 u4; } z;
  const float* src = Wqk_t + (size_t)n*HH + kk*32 + qq*8;
  #pragma unroll
  for(int j=0;j<8;j++) z.h[j] = (f16)src[j];
  ((uint4*)Wfm)[((size_t)nt*16 + kk)*64 + L] = z.u4;
}

// ---------------------------------------------------------------------------
// Persistent kernel: 256 blocks = 8 pairs x 32 roles. Pair owns 2 groups of
// 16 batch rows (A,B) sharing weight fragments; role owns 16 h-cols.
// Each block owns exactly one private attention row battn.
// ---------------------------------------------------------------------------
__global__ void __launch_bounds__(256, 1)
persist(const float* __restrict__ einp, const f16* __restrict__ Wenc,
        const f16* __restrict__ Wdec, const f16* __restrict__ Wqf,
        const float* __restrict__ bd, const float* __restrict__ bqk,
        f16* __restrict__ hb0, f16* __restrict__ hb1, f16* __restrict__ hx,
        f16* __restrict__ ctxg, float* __restrict__ qtx,
        const float* __restrict__ outW, const float* __restrict__ outb,
        float* __restrict__ out, u32* __restrict__ bar){
  __shared__ f16 stA[16*STRD];          // 33,280 B
  __shared__ f16 stB[16*STRD];          // 33,280 B
  __shared__ f16 abuf0[16*520];         // 16,640 B (attn tile buffers)
  __shared__ f16 abuf1[16*520];         // 16,640 B
  __shared__ float gtA[64][17];         // 4,352 B
  __shared__ float gtB[64][17];         // 4,352 B
  __shared__ __align__(16) float qsh[512];
  __shared__ float sc[16];

  const int tid  = threadIdx.x;
  const int pair = blockIdx.x >> 5;     // 8 pairs
  const int role = blockIdx.x & 31;     // 32 roles (16 h-cols each)
  const int bA0 = pair*32, bB0 = pair*32 + 16;
  const int lane = tid & 63, w = tid >> 6;        // wave = gate
  const int m = lane & 15, q = lane >> 4;
  const int grp = tid >> 7;                       // epilogue: 0=A, 1=B
  const int erow = (tid & 127) >> 3;              // epilogue row 0..15
  const int ec2  = (tid & 7) * 2;                 // epilogue col pair
  const int battn = (role < 16) ? (bA0 + role) : (bB0 + role - 16);
  const int seg = tid & 15, sp = tid >> 4;        // attn score map
  u32* pb = bar + (size_t)pair*4096;
  f16* hb[2] = {hb0, hb1};

  // encoder B fragments (gate w, this role) — shared by both groups
  f16x8 Be[17];
  {
    const f16x8* wp = (const f16x8*)Wenc + ((size_t)(w*32+role)*17)*64 + lane;
    #pragma unroll
    for(int kk=0;kk<17;kk++) Be[kk] = wp[kk*64];
  }
  float c0 = 0.f, c1 = 0.f;   // cell state for thread's 2 cols (its group)

  const int sc_ = tid & 127, sr0 = tid >> 7;   // staging map: col, row-base

  // ===================== ENCODER (512 steps) =====================
  for(int t=0; t<SS; ++t){
    if(t){ // group barrier (all threads poll)
      u32* sl = pb + (t-1);
      while(__hip_atomic_load(sl, __ATOMIC_RELAXED, __HIP_MEMORY_SCOPE_AGENT) < 32u)
        __builtin_amdgcn_s_sleep(1);
    }
    { // stage h(t) both groups: 16 rows x 512 f16 each, sc1 u64
      const u64* sa = (const u64*)(hb[t&1] + (size_t)bA0*HH);
      const u64* sb = (const u64*)(hb[t&1] + (size_t)bB0*HH);
      #pragma unroll
      for(int i=0;i<8;i++){
        int row = sr0 + 2*i;
        u64 va = xld(sa + row*128 + sc_);
        u64 vb = xld(sb + row*128 + sc_);
        *(u64*)(stA + row*STRD + sc_*4) = va;
        *(u64*)(stB + row*STRD + sc_*4) = vb;
      }
    }
    if(tid < 128){ // ext cols 512..543 = [e, 1, 0...] for both groups
      int row = tid>>3, j = tid&7;
      u64 za = 0, zb = 0;
      if(j==0){
        union{ u64 u; f16 h[4]; } p; p.u = 0;
        p.h[0] = (f16)einp[(size_t)(bA0+row)*SS + t]; p.h[1] = (f16)1.0f; za = p.u;
        p.h[0] = (f16)einp[(size_t)(bB0+row)*SS + t]; zb = p.u;
      }
      *(u64*)(stA + row*STRD + 512 + j*4) = za;
      *(u64*)(stB + row*STRD + 512 + j*4) = zb;
    }
    __syncthreads();

    // private hx row write (h output of step t-1) from staged h
    if(t > 0 && tid < 64){
      const f16* src = (role < 16) ? (stA + (role)*STRD) : (stB + (role-16)*STRD);
      ((uint4*)(hx + ((size_t)battn*SS + (t-1))*HH))[tid] = ((const uint4*)src)[tid];
    }

    f32x4 aA = {0.f,0.f,0.f,0.f}, aB = {0.f,0.f,0.f,0.f};
    {
      const f16* arA = stA + m*STRD + q*8;
      const f16* arB = stB + m*STRD + q*8;
      #pragma unroll
      for(int kk=0;kk<17;kk++){
        f16x8 xa = *(const f16x8*)(arA + kk*32);
        f16x8 xb = *(const f16x8*)(arB + kk*32);
        aA = __builtin_amdgcn_mfma_f32_16x16x32_f16(xa, Be[kk], aA, 0,0,0);
        aB = __builtin_amdgcn_mfma_f32_16x16x32_f16(xb, Be[kk], aB, 0,0,0);
      }
    }
    #pragma unroll
    for(int r=0;r<4;r++){
      gtA[w*16+m][q*4+r] = aA[r];    // [gate*16+col][batch]
      gtB[w*16+m][q*4+r] = aB[r];
    }
    __syncthreads();

    { // epilogue: grp half-split; thread owns (erow, ec2), (erow, ec2+1)
      float (*gt)[17] = grp ? gtB : gtA;
      float gi0=gt[ec2][erow],    gi1=gt[ec2+1][erow];
      float gf0=gt[16+ec2][erow], gf1=gt[17+ec2][erow];
      float gg0=gt[32+ec2][erow], gg1=gt[33+ec2][erow];
      float go0=gt[48+ec2][erow], go1=gt[49+ec2][erow];
      float cv0 = sigm(gf0)*c0 + sigm(gi0)*tanh_f(gg0); c0 = cv0;
      float cv1 = sigm(gf1)*c1 + sigm(gi1)*tanh_f(gg1); c1 = cv1;
      float hv0 = sigm(go0)*tanh_f(cv0);
      float hv1 = sigm(go1)*tanh_f(cv1);
      union { u32 u; f16 h[2]; } pk;
      pk.h[0] = (f16)hv0; pk.h[1] = (f16)hv1;
      int b = (grp ? bB0 : bA0) + erow;
      xst((u32*)(hb[(t+1)&1] + (size_t)b*HH + role*16 + ec2), pk.u);
    }
    __syncthreads();          // drains all waves' stores (vmcnt(0) at barrier)
    if(tid == 0)
      __hip_atomic_fetch_add(pb + t, 1u, __ATOMIC_RELAXED, __HIP_MEMORY_SCOPE_AGENT);
  }

  // wait final encoder step, write last hx row (h after step 511, in hb[0])
  {
    u32* sl = pb + (SS-1);
    while(__hip_atomic_load(sl, __ATOMIC_RELAXED, __HIP_MEMORY_SCOPE_AGENT) < 32u)
      __builtin_amdgcn_s_sleep(1);
  }
  if(tid < 128){
    u64 v = xld((const u64*)(hb0 + (size_t)battn*HH) + tid);
    *(u64*)(hx + ((size_t)battn*SS + (SS-1))*HH + tid*4) = v;
  }

  // decoder weights + scalars
  f16x8 Bd[32];
  {
    const f16x8* wp = (const f16x8*)Wdec + ((size_t)(w*32+role)*32)*64 + lane;
    #pragma unroll
    for(int kk=0;kk<32;kk++) Bd[kk] = wp[kk*64];
  }
  const float bdv = bd[w*HH + role*16 + m];
  const float bqv = bqk[role*16 + m];
  const float ow0 = outW[role*16 + ec2];
  const float ow1 = outW[role*16 + ec2 + 1];
  const float ob0 = outb[0];
  const uint4* hrow = (const uint4*)(hx + (size_t)battn*SS*HH);  // private, plain loads

  // ===================== DECODER (96 steps) =====================
  for(int t=0; t<TT; ++t){
    if(t){
      u32* sl = pb + (SS + 3*(t-1) + 2);
      while(__hip_atomic_load(sl, __ATOMIC_RELAXED, __HIP_MEMORY_SCOPE_AGENT) < 32u)
        __builtin_amdgcn_s_sleep(1);
    }
    { // ph1: stage h(t) both groups (512 cols)
      const u64* sa = (const u64*)(hb[t&1] + (size_t)bA0*HH);
      const u64* sb = (const u64*)(hb[t&1] + (size_t)bB0*HH);
      #pragma unroll
      for(int i=0;i<8;i++){
        int row = sr0 + 2*i;
        u64 va = xld(sa + row*128 + sc_);
        u64 vb = xld(sb + row*128 + sc_);
        *(u64*)(stA + row*STRD + sc_*4) = va;
        *(u64*)(stB + row*STRD + sc_*4) = vb;
      }
    }
    __syncthreads();
    if(w < 2){ // qproj: wave0 -> group A, wave1 -> group B
      const f16* ar = (w ? stB : stA) + m*STRD + q*8;
      const f16x8* wq = (const f16x8*)Wqf + ((size_t)role*16)*64 + lane;
      f32x4 aq = {bqv,bqv,bqv,bqv};
      #pragma unroll
      for(int kk=0;kk<16;kk++){
        f16x8 x = *(const f16x8*)(ar + kk*32);
        aq = __builtin_amdgcn_mfma_f32_16x16x32_f16(x, wq[kk*64], aq, 0,0,0);
      }
      int b0q = w ? bB0 : bA0;
      #pragma unroll
      for(int r=0;r<4;r++)
        xst((u32*)(qtx + (size_t)(b0q + q*4 + r)*HH + role*16 + m),
            __float_as_uint(aq[r]));
    }
    __syncthreads();
    if(tid == 0)
      __hip_atomic_fetch_add(pb + (SS + 3*t), 1u, __ATOMIC_RELAXED, __HIP_MEMORY_SCOPE_AGENT);

    // prefetch attn tiles 0,1 (private hx, plain loads) BEFORE the Q poll
    uint4 ra[4], rb[4];
    #pragma unroll
    for(int j=0;j<4;j++) ra[j] = hrow[j*256 + tid];
    #pragma unroll
    for(int j=0;j<4;j++) rb[j] = hrow[1024 + j*256 + tid];
    {
      u32* sl = pb + (SS + 3*t);
      while(__hip_atomic_load(sl, __ATOMIC_RELAXED, __HIP_MEMORY_SCOPE_AGENT) < 32u)
        __builtin_amdgcn_s_sleep(1);
    }
    // q row for battn -> LDS -> regs
    {
      u64 v = xld((const u64*)(qtx + (size_t)battn*HH) + tid);
      *(u64*)(qsh + 2*tid) = v;
    }
    __syncthreads();
    float2 qreg[16];
    #pragma unroll
    for(int k=0;k<16;k++) qreg[k] = *(const float2*)&qsh[2*(seg + 16*k)];

    // flash attention over 32 tiles of 16 rows, double-buffered
    float mm = -1e30f, ll = 0.f, aa0 = 0.f, aa1 = 0.f;

#define WRITE_TILE(BUF, R) { \
    _Pragma("unroll") \
    for(int j=0;j<4;j++){ int e = j*256 + tid; \
      *(uint4*)((BUF) + (e>>6)*520 + (e&63)*8) = R[j]; } }
#define LOAD_TILE(R, IT) { \
    _Pragma("unroll") \
    for(int j=0;j<4;j++) R[j] = hrow[(size_t)(IT)*1024 + j*256 + tid]; }
#define ATTN_TILE(BUF) { \
    __syncthreads(); \
    const u32* xs32 = (const u32*)(BUF); \
    float p = 0.f; \
    const u32* xr = xs32 + sp*260; \
    _Pragma("unroll") \
    for(int k=0;k<16;k++){ float2 xv = cvt2(xr[seg + 16*k]); \
      p = fmaf(qreg[k].x, xv.x, p); p = fmaf(qreg[k].y, xv.y, p); } \
    p += __shfl_xor(p,1); p += __shfl_xor(p,2); \
    p += __shfl_xor(p,4); p += __shfl_xor(p,8); \
    if(seg==0) sc[sp] = p; \
    __syncthreads(); \
    float tmax = sc[0]; \
    _Pragma("unroll") \
    for(int s2=1;s2<16;s2++) tmax = fmaxf(tmax, sc[s2]); \
    float mnew = fmaxf(mm, tmax); \
    float alpha = __expf(mm - mnew); \
    aa0 *= alpha; aa1 *= alpha; ll *= alpha; \
    _Pragma("unroll") \
    for(int s2=0;s2<16;s2++){ float pv = __expf(sc[s2] - mnew); ll += pv; \
      float2 xf = cvt2(xs32[s2*260 + tid]); \
      aa0 = fmaf(pv, xf.x, aa0); aa1 = fmaf(pv, xf.y, aa1); } \
    mm = mnew; }

    for(int it=0; it<32; it+=2){
      WRITE_TILE(abuf0, ra);
      if(it+2 < 32) LOAD_TILE(ra, it+2);
      ATTN_TILE(abuf0);
      WRITE_TILE(abuf1, rb);
      if(it+3 < 32) LOAD_TILE(rb, it+3);
      ATTN_TILE(abuf1);
    }
#undef WRITE_TILE
#undef LOAD_TILE
#undef ATTN_TILE

    { // ctx store (cols 2*tid, 2*tid+1)
      float inv = 1.0f/ll;
      union { u32 u; f16 h[2]; } pk;
      pk.h[0] = (f16)(aa0*inv); pk.h[1] = (f16)(aa1*inv);
      xst((u32*)(ctxg + (size_t)battn*HH + 2*tid), pk.u);
    }
    __syncthreads();
    if(tid == 0)
      __hip_atomic_fetch_add(pb + (SS + 3*t + 1), 1u, __ATOMIC_RELAXED, __HIP_MEMORY_SCOPE_AGENT);
    {
      u32* sl = pb + (SS + 3*t + 1);
      while(__hip_atomic_load(sl, __ATOMIC_RELAXED, __HIP_MEMORY_SCOPE_AGENT) < 32u)
        __builtin_amdgcn_s_sleep(1);
    }

    { // ph3: stage ctx into cols 512..1023 (h cols 0..511 still staged from ph1)
      const u64* ca = (const u64*)(ctxg + (size_t)bA0*HH);
      const u64* cb = (const u64*)(ctxg + (size_t)bB0*HH);
      #pragma unroll
      for(int i=0;i<8;i++){
        int row = sr0 + 2*i;
        u64 va = xld(ca + row*128 + sc_);
        u64 vb = xld(cb + row*128 + sc_);
        *(u64*)(stA + row*STRD + 512 + sc_*4) = va;
        *(u64*)(stB + row*STRD + 512 + sc_*4) = vb;
      }
    }
    __syncthreads();

    f32x4 aA = {bdv,bdv,bdv,bdv}, aB = {bdv,bdv,bdv,bdv};
    {
      const f16* arA = stA + m*STRD + q*8;
      const f16* arB = stB + m*STRD + q*8;
      #pragma unroll
      for(int kk=0;kk<32;kk++){
        f16x8 xa = *(const f16x8*)(arA + kk*32);
        f16x8 xb = *(const f16x8*)(arB + kk*32);
        aA = __builtin_amdgcn_mfma_f32_16x16x32_f16(xa, Bd[kk], aA, 0,0,0);
        aB = __builtin_amdgcn_mfma_f32_16x16x32_f16(xb, Bd[kk], aB, 0,0,0);
      }
    }
    #pragma unroll
    for(int r=0;r<4;r++){
      gtA[w*16+m][q*4+r] = aA[r];
      gtB[w*16+m][q*4+r] = aB[r];
    }
    __syncthreads();

    { // epilogue + fused output GEMV partial
      float (*gt)[17] = grp ? gtB : gtA;
      float gi0=gt[ec2][erow],    gi1=gt[ec2+1][erow];
      float gf0=gt[16+ec2][erow], gf1=gt[17+ec2][erow];
      float gg0=gt[32+ec2][erow], gg1=gt[33+ec2][erow];
      float go0=gt[48+ec2][erow], go1=gt[49+ec2][erow];
      float cv0 = sigm(gf0)*c0 + sigm(gi0)*tanh_f(gg0); c0 = cv0;
      float cv1 = sigm(gf1)*c1 + sigm(gi1)*tanh_f(gg1); c1 = cv1;
      float hv0 = sigm(go0)*tanh_f(cv0);
      float hv1 = sigm(go1)*tanh_f(cv1);
      union { u32 u; f16 h[2]; } pk;
      pk.h[0] = (f16)hv0; pk.h[1] = (f16)hv1;
      int b = (grp ? bB0 : bA0) + erow;
      xst((u32*)(hb[(t+1)&1] + (size_t)b*HH + role*16 + ec2), pk.u);
      float po = hv0*ow0 + hv1*ow1;
      po += __shfl_xor(po, 1);
      po += __shfl_xor(po, 2);
      po += __shfl_xor(po, 4);
      if((tid & 7) == 0){
        float bias = (role == 0) ? ob0 : 0.f;
        atomicAdd(&out[(size_t)b*TT + t], po + bias);
      }
    }
    __syncthreads();
    if(tid == 0)
      __hip_atomic_fetch_add(pb + (SS + 3*t + 2), 1u, __ATOMIC_RELAXED, __HIP_MEMORY_SCOPE_AGENT);
  }
}

// ---------------------------------------------------------------------------
extern "C" void kernel_launch(void* const* d_in, const int* in_sizes, int n_in,
                              void* d_out, int out_size, void* d_ws, size_t ws_size,
                              hipStream_t stream){
  const float* enc_in = (const float*)d_in[0];
  const float* embW = (const float*)d_in[2];
  const float* embB = (const float*)d_in[3];
  const float* eWih = (const float*)d_in[4];
  const float* eWhh = (const float*)d_in[5];
  const float* ebih = (const float*)d_in[6];
  const float* ebhh = (const float*)d_in[7];
  const float* dWih = (const float*)d_in[8];
  const float* dWhh = (const float*)d_in[9];
  const float* dbih = (const float*)d_in[10];
  const float* dbhh = (const float*)d_in[11];
  const float* Wq   = (const float*)d_in[12];
  const float* bq   = (const float*)d_in[13];
  const float* Wk   = (const float*)d_in[14];
  // d_in[15]: bk — softmax-invariant, unused
  const float* outW = (const float*)d_in[16];
  const float* outb = (const float*)d_in[17];

  char* base = (char*)d_ws;
  f16* Wenc   = (f16*)(base + 0);            // 2,228,224
  f16* Wdec   = (f16*)(base + 2228224);      // 4,194,304
  f16* Wqf    = (f16*)(base + 6422528);      //   524,288
  f16* hb0    = (f16*)(base + 6946816);      //   262,144
  f16* hb1    = (f16*)(base + 7208960);      //   262,144
  f16* ctxg   = (f16*)(base + 7471104);      //   262,144
  float* qtx  = (float*)(base + 7733248);    //   524,288
  float* Wqk_t= (float*)(base + 8257536);    // 1,048,576
  float* u    = (float*)(base + 9306112);    //     8,192
  float* v    = (float*)(base + 9314304);    //     8,192
  float* bd   = (float*)(base + 9322496);    //     8,192
  float* bqk  = (float*)(base + 9330688);    //     2,048
  u32* bar    = (u32*)(base + 9332736);      //   131,072 (8 pairs x 4096)
  f16* hx     = (f16*)(base + 9568256);      // 134,217,728 -> ends ~143.8 MB

  hipMemsetAsync(hb0, 0, (size_t)BB*HH*sizeof(f16), stream);
  hipMemsetAsync(bar, 0, 8*4096*sizeof(u32), stream);
  hipMemsetAsync(d_out, 0, (size_t)out_size*sizeof(float), stream);

  prep_uv  <<<8, 256, 0, stream>>>(eWih, embW, embB, ebih, ebhh, dbih, dbhh, u, v, bd);
  prep_bqk <<<2, 256, 0, stream>>>(bq, Wk, bqk);
  prep_wqk <<<512, 256, 0, stream>>>(Wq, Wk, Wqk_t);
  prep_wenc<<<dim3(128,17), 64, 0, stream>>>(eWhh, u, v, Wenc);
  prep_wdec<<<dim3(128,32), 64, 0, stream>>>(dWih, dWhh, Wdec);
  prep_wqfm<<<dim3(32,16),  64, 0, stream>>>(Wqk_t, Wqf);

  persist<<<256, 256, 0, stream>>>(enc_in, Wenc, Wdec, Wqf, bd, bqk,
                                   hb0, hb1, hx, ctxg, qtx,
                                   outW, outb, (float*)d_out, bar);
}

// Round 6
// 9830.561 us; speedup vs baseline: 1.5691x; 1.0404x over previous
//
#include <hip/hip_runtime.h>
#include <hip/hip_bf16.h>
#include <cstdint>
#include <cstddef>

#define BB   256   // batch
#define SS   512   // encoder seq len
#define RDIM 128   // embed dim
#define HH   512   // hidden
#define TT   96    // decoder steps
#define STRD 1048  // f16 LDS row stride (524 dw; mfma b128 A-reads conflict-free)

typedef unsigned int u32;
typedef unsigned long long u64;
typedef _Float16 f16;
typedef __attribute__((ext_vector_type(8))) _Float16 f16x8;
typedef __attribute__((ext_vector_type(4))) float f32x4;

__device__ __forceinline__ float sigm(float x){ return 1.0f/(1.0f+__expf(-x)); }
__device__ __forceinline__ float tanh_f(float x){ return 1.0f - 2.0f/(__expf(2.0f*x)+1.0f); }
__device__ __forceinline__ float2 cvt2(u32 x){
  union { u32 u; f16 h[2]; } t; t.u = x;
  return make_float2((float)t.h[0], (float)t.h[1]);
}
// relaxed agent-scope (MALL-coherent, no cache flush instructions)
__device__ __forceinline__ u64 xld(const u64* p){
  return __hip_atomic_load(p, __ATOMIC_RELAXED, __HIP_MEMORY_SCOPE_AGENT);
}
__device__ __forceinline__ void xst(u32* p, u32 v){
  __hip_atomic_store(p, v, __ATOMIC_RELAXED, __HIP_MEMORY_SCOPE_AGENT);
}

// ---------------------------------------------------------------------------
// Prep kernels (unchanged mappings)
// ---------------------------------------------------------------------------
__global__ void prep_uv(const float* __restrict__ Wih, const float* __restrict__ embW,
                        const float* __restrict__ embB, const float* __restrict__ bih,
                        const float* __restrict__ bhh, const float* __restrict__ dbih,
                        const float* __restrict__ dbhh,
                        float* __restrict__ u, float* __restrict__ v, float* __restrict__ bd){
  int n = blockIdx.x*256 + threadIdx.x;
  const float* row = Wih + (size_t)n*RDIM;
  float su = 0.f, sv = 0.f;
  for(int r=0;r<RDIM;r++){ float w = row[r]; su += w*embW[r]; sv += w*embB[r]; }
  u[n] = su;
  v[n] = sv + bih[n] + bhh[n];
  bd[n] = dbih[n] + dbhh[n];
}

__global__ void prep_wqk(const float* __restrict__ Wq, const float* __restrict__ Wk,
                         float* __restrict__ Wqk_t){
  __shared__ float wkc[HH];
  int n = blockIdx.x;
  for(int i=threadIdx.x;i<HH;i+=256) wkc[i] = Wk[(size_t)i*HH + n];
  __syncthreads();
  for(int a=threadIdx.x;a<HH;a+=256){
    float s = 0.f;
    for(int hp=0;hp<HH;hp++) s += Wq[(size_t)hp*HH + a]*wkc[hp];
    Wqk_t[(size_t)n*HH + a] = s;
  }
}

__global__ void prep_bqk(const float* __restrict__ bq, const float* __restrict__ Wk,
                         float* __restrict__ bqk){
  int n = blockIdx.x*256 + threadIdx.x;
  float s = 0.f;
  for(int hp=0;hp<HH;hp++) s += bq[hp]*Wk[(size_t)hp*HH + n];
  bqk[n] = s;
}

// nt = gate*32 + role: n = gate*512 + role*16 + (L&15); kk16 ext = [u,v,0..]
__global__ void prep_wenc(const float* __restrict__ Whh, const float* __restrict__ u,
                          const float* __restrict__ v, f16* __restrict__ Wfm){
  int nt = blockIdx.x, kk = blockIdx.y, L = threadIdx.x;   // (128,17), 64 thr
  int n = (nt>>5)*HH + (nt&31)*16 + (L&15);
  int qq = L>>4;
  union { f16 h[8]; uint4 u4; } z;
  if(kk < 16){
    const float* src = Whh + (size_t)n*HH + kk*32 + qq*8;
    #pragma unroll
    for(int j=0;j<8;j++) z.h[j] = (f16)src[j];
  } else {
    #pragma unroll
    for(int j=0;j<8;j++) z.h[j] = (f16)0.0f;
    if(qq==0){ z.h[0] = (f16)u[n]; z.h[1] = (f16)v[n]; }
  }
  ((uint4*)Wfm)[((size_t)nt*17 + kk)*64 + L] = z.u4;
}

__global__ void prep_wdec(const float* __restrict__ dWih, const float* __restrict__ dWhh,
                          f16* __restrict__ Wfm){
  int nt = blockIdx.x, kk = blockIdx.y, L = threadIdx.x;   // (128,32), 64 thr
  int n = (nt>>5)*HH + (nt&31)*16 + (L&15);
  int qq = L>>4;
  int k0 = kk*32 + qq*8;
  union { f16 h[8]; uint4 u4; } z;
  #pragma unroll
  for(int j=0;j<8;j++){
    float wv = dWih[(size_t)n*1024 + k0 + j];
    if(k0 + j < HH) wv += dWhh[(size_t)n*HH + k0 + j];
    z.h[j] = (f16)wv;
  }
  ((uint4*)Wfm)[((size_t)nt*32 + kk)*64 + L] = z.u4;
}

__global__ void prep_wqfm(const float* __restrict__ Wqk_t, f16* __restrict__ Wfm){
  int nt = blockIdx.x, kk = blockIdx.y, L = threadIdx.x;   // (32,16), 64 thr
  int n = nt*16 + (L&15);
  int qq = L>>4;
  union { f16 h[8]; uint4 u4; } z;
  const float* src = Wqk_t + (size_t)n*HH + kk*32 + qq*8;
  #pragma unroll
  for(int j=0;j<8;j++) z.h[j] = (f16)src[j];
  ((uint4*)Wfm)[((size_t)nt*16 + kk)*64 + L] = z.u4;
}

// ---------------------------------------------------------------------------
// Flag-vector barrier: producer posts its role's flag (single store, no RMW);
// consumers poll all 32 flags with one coalesced load + __all vote.
// ---------------------------------------------------------------------------
__device__ __forceinline__ void post_flag(u32* slot, u32 tag){
  __syncthreads();   // all waves drain their vmem stores before the flag
  if(threadIdx.x == 0)
    __hip_atomic_store(slot, tag, __ATOMIC_RELAXED, __HIP_MEMORY_SCOPE_AGENT);
}
__device__ __forceinline__ void wait_flags(const u32* f, u32 tag){
  const u32* p = f + (threadIdx.x & 31);
  while(true){
    u32 v = __hip_atomic_load(p, __ATOMIC_RELAXED, __HIP_MEMORY_SCOPE_AGENT);
    if(__all((int)(v >= tag))) break;
    __builtin_amdgcn_s_sleep(2);
  }
}

// ---------------------------------------------------------------------------
// Persistent kernel: 256 blocks = 8 pairs x 32 roles. Pair owns 32 batch rows
// (groups A,B of 16) sharing register weights; role owns 16 h-cols. Encoder h
// goes ONLY to the write-once ring hxT[t][b][h] (= attention KV), staged back
// with plain cached loads (L2 multicast). Attention is register-direct flash.
// ---------------------------------------------------------------------------
__global__ void __launch_bounds__(256, 1)
persist(const float* __restrict__ einp, const f16* __restrict__ Wenc,
        const f16* __restrict__ Wdec, const f16* __restrict__ Wqf,
        const float* __restrict__ bd, const float* __restrict__ bqk,
        f16* __restrict__ hxT, f16* __restrict__ hdb, f16* __restrict__ ctxg,
        float* __restrict__ qtx, const float* __restrict__ outW,
        const float* __restrict__ outb, float* __restrict__ out,
        u32* __restrict__ flags){
  __shared__ f16 stA[16*STRD];            // 33,536 B
  __shared__ f16 stB[16*STRD];            // 33,536 B
  __shared__ float gtA[64][18];           // 4,608 B
  __shared__ float gtB[64][18];           // 4,608 B
  __shared__ __align__(16) float qsh[512];
  __shared__ float scb[2][16];
  __shared__ float cp[4][512];            // 8,192 B cross-wave PV reduce

  const int tid  = threadIdx.x;
  const int pair = blockIdx.x >> 5;
  const int role = blockIdx.x & 31;
  const int b0 = pair*32;
  const int lane = tid & 63, w = tid >> 6;        // wave = gate
  const int m = lane & 15, q = lane >> 4;
  const int grp = tid >> 7;                       // epilogue: 0=A, 1=B
  const int erow = (tid & 127) >> 3;              // epilogue row 0..15
  const int ec2  = (tid & 7) * 2;                 // epilogue col pair
  const int battn = b0 + role;                    // private attention row
  u32* fE = flags + (size_t)pair*256;
  u32* fQ = fE + 32;
  u32* fC = fE + 64;
  u32* fH = fE + 96;

  // encoder B fragments in registers (shared by both groups)
  f16x8 Be[17];
  {
    const f16x8* wp = (const f16x8*)Wenc + ((size_t)(w*32+role)*17)*64 + lane;
    #pragma unroll
    for(int kk=0;kk<17;kk++) Be[kk] = wp[kk*64];
  }
  float c0 = 0.f, c1 = 0.f;   // cell state, register-resident for all 608 steps

  // ===================== ENCODER (512 steps) =====================
  for(int t=0; t<SS; ++t){
    if(t) wait_flags(fE, (u32)t);
    if(t == 0){
      uint4 z = make_uint4(0,0,0,0);
      #pragma unroll
      for(int i=0;i<8;i++){
        int e = i*256 + tid, row = e>>6, c16 = e&63;
        *(uint4*)((row<16?stA:stB) + (row&15)*STRD + c16*8) = z;
      }
    } else {
      const uint4* src = (const uint4*)(hxT + ((size_t)(t-1)*BB + b0)*HH);
      #pragma unroll
      for(int i=0;i<8;i++){
        int e = i*256 + tid, row = e>>6, c16 = e&63;
        uint4 vv = src[e];                           // plain: write-once data
        *(uint4*)((row<16?stA:stB) + (row&15)*STRD + c16*8) = vv;
      }
    }
    if(tid < 128){   // ext cols 512..543 = [e_t, 1, 0...]
      int row = tid>>2, pc = tid&3;
      union { f16 h[8]; uint4 u4; } z;
      #pragma unroll
      for(int j=0;j<8;j++) z.h[j] = (f16)0.0f;
      if(pc==0){ z.h[0] = (f16)einp[(size_t)(b0+row)*SS + t]; z.h[1] = (f16)1.0f; }
      *(uint4*)((row<16?stA:stB) + (row&15)*STRD + 512 + pc*8) = z.u4;
    }
    __syncthreads();

    f32x4 aA = {0.f,0.f,0.f,0.f}, aB = {0.f,0.f,0.f,0.f};
    {
      const f16* arA = stA + m*STRD + q*8;
      const f16* arB = stB + m*STRD + q*8;
      #pragma unroll
      for(int kk=0;kk<17;kk++){
        f16x8 xa = *(const f16x8*)(arA + kk*32);
        f16x8 xb = *(const f16x8*)(arB + kk*32);
        aA = __builtin_amdgcn_mfma_f32_16x16x32_f16(xa, Be[kk], aA, 0,0,0);
        aB = __builtin_amdgcn_mfma_f32_16x16x32_f16(xb, Be[kk], aB, 0,0,0);
      }
    }
    #pragma unroll
    for(int r=0;r<4;r++){
      gtA[w*16+m][q*4+r] = aA[r];   // C/D: col=lane&15, row=q*4+r
      gtB[w*16+m][q*4+r] = aB[r];
    }
    __syncthreads();

    { // epilogue -> h slice straight into hxT[t]
      float (*gt)[18] = grp ? gtB : gtA;
      float gi0=gt[ec2][erow],    gi1=gt[ec2+1][erow];
      float gf0=gt[16+ec2][erow], gf1=gt[17+ec2][erow];
      float gg0=gt[32+ec2][erow], gg1=gt[33+ec2][erow];
      float go0=gt[48+ec2][erow], go1=gt[49+ec2][erow];
      float cv0 = sigm(gf0)*c0 + sigm(gi0)*tanh_f(gg0); c0 = cv0;
      float cv1 = sigm(gf1)*c1 + sigm(gi1)*tanh_f(gg1); c1 = cv1;
      float hv0 = sigm(go0)*tanh_f(cv0);
      float hv1 = sigm(go1)*tanh_f(cv1);
      union { u32 u; f16 h[2]; } pk;
      pk.h[0] = (f16)hv0; pk.h[1] = (f16)hv1;
      int b = b0 + grp*16 + erow;
      xst((u32*)(hxT + ((size_t)t*BB + b)*HH + role*16 + ec2), pk.u);
    }
    post_flag(&fE[role], (u32)(t+1));
  }

  // decoder weights + scalars
  f16x8 Bd[32];
  {
    const f16x8* wp = (const f16x8*)Wdec + ((size_t)(w*32+role)*32)*64 + lane;
    #pragma unroll
    for(int kk=0;kk<32;kk++) Bd[kk] = wp[kk*64];
  }
  const float bdv = bd[w*HH + role*16 + m];
  const float bqv = bqk[role*16 + m];
  const float ow0 = outW[role*16 + ec2];
  const float ow1 = outW[role*16 + ec2 + 1];
  const float ob0 = outb[0];
  const f16x8* WqfP = (const f16x8*)Wqf + ((size_t)role*16)*64 + lane;

  // ===================== DECODER (96 steps) =====================
  for(int t=0; t<TT; ++t){
    if(t == 0) wait_flags(fE, (u32)SS);
    else       wait_flags(fH, (u32)t);

    { // ph1: stage h(t) both groups (sc1 for hdb; hxT[511] also via sc1 path)
      const u64* hsrc = (t==0) ? (const u64*)(hxT + ((size_t)(SS-1)*BB + b0)*HH)
                               : (const u64*)(hdb + (size_t)b0*HH);
      #pragma unroll
      for(int i=0;i<16;i++){
        int e = i*256 + tid, row = e>>7, c8 = e&127;
        u64 vv = xld(hsrc + (size_t)row*128 + c8);
        *(u64*)((row<16?stA:stB) + (row&15)*STRD + c8*4) = vv;
      }
    }
    __syncthreads();
    if(w < 2){ // qproj: wave0 -> group A rows, wave1 -> group B rows
      const f16* ar = (w ? stB : stA) + m*STRD + q*8;
      f32x4 aq = {bqv,bqv,bqv,bqv};
      #pragma unroll
      for(int kk=0;kk<16;kk++){
        f16x8 x = *(const f16x8*)(ar + kk*32);
        aq = __builtin_amdgcn_mfma_f32_16x16x32_f16(x, WqfP[kk*64], aq, 0,0,0);
      }
      #pragma unroll
      for(int r=0;r<4;r++)
        xst((u32*)(qtx + (size_t)(b0 + w*16 + q*4 + r)*HH + role*16 + m),
            __float_as_uint(aq[r]));
    }
    post_flag(&fQ[role], (u32)(t+1));

    // prefetch attn tiles 0..3 (private hxT row, plain loads — read-only data)
    uint4 rt[4][4];
    #pragma unroll
    for(int slot=0;slot<4;slot++)
      #pragma unroll
      for(int j=0;j<4;j++)
        rt[slot][j] = *(const uint4*)(hxT +
            ((size_t)(slot*16 + 4*j + w)*BB + battn)*HH + lane*8);

    // gates part1 (h half of K) — hides q-flag propagation
    f32x4 aA = {bdv,bdv,bdv,bdv}, aB = {bdv,bdv,bdv,bdv};
    {
      const f16* arA = stA + m*STRD + q*8;
      const f16* arB = stB + m*STRD + q*8;
      #pragma unroll
      for(int kk=0;kk<16;kk++){
        f16x8 xa = *(const f16x8*)(arA + kk*32);
        f16x8 xb = *(const f16x8*)(arB + kk*32);
        aA = __builtin_amdgcn_mfma_f32_16x16x32_f16(xa, Bd[kk], aA, 0,0,0);
        aB = __builtin_amdgcn_mfma_f32_16x16x32_f16(xb, Bd[kk], aB, 0,0,0);
      }
    }

    wait_flags(fQ, (u32)(t+1));
    {
      u64 vq = xld((const u64*)(qtx + (size_t)battn*HH) + tid);
      *(u64*)(qsh + 2*tid) = vq;
    }
    __syncthreads();
    float q8[8];
    #pragma unroll
    for(int c=0;c<8;c++) q8[c] = qsh[lane*8 + c];

    // ---- register-direct flash attention, 32 tiles of 16 rows ----
    float mm = -1e30f, l = 0.f, acc8[8];
    #pragma unroll
    for(int c=0;c<8;c++) acc8[c] = 0.f;

    for(int it=0; it<32; ++it){
      int slot = it & 3;
      float pj[4];
      #pragma unroll
      for(int j=0;j<4;j++){
        uint4 v = rt[slot][j];
        float2 x0=cvt2(v.x), x1=cvt2(v.y), x2=cvt2(v.z), x3=cvt2(v.w);
        float p = q8[0]*x0.x;
        p = fmaf(q8[1],x0.y,p); p = fmaf(q8[2],x1.x,p); p = fmaf(q8[3],x1.y,p);
        p = fmaf(q8[4],x2.x,p); p = fmaf(q8[5],x2.y,p);
        p = fmaf(q8[6],x3.x,p); p = fmaf(q8[7],x3.y,p);
        #pragma unroll
        for(int k=1;k<64;k<<=1) p += __shfl_xor(p, k);
        pj[j] = p;
      }
      if(lane == 0){
        #pragma unroll
        for(int j=0;j<4;j++) scb[it&1][4*j+w] = pj[j];
      }
      __syncthreads();
      float tmax = scb[it&1][0];
      #pragma unroll
      for(int s2=1;s2<16;s2++) tmax = fmaxf(tmax, scb[it&1][s2]);
      float mnew = fmaxf(mm, tmax);
      float alpha = __expf(mm - mnew);
      #pragma unroll
      for(int c=0;c<8;c++) acc8[c] *= alpha;
      l *= alpha;
      float pvj[4] = {0.f,0.f,0.f,0.f};
      #pragma unroll
      for(int s2=0;s2<16;s2++){
        float pv = __expf(scb[it&1][s2] - mnew);
        l += pv;
        if((s2&3) == w) pvj[s2>>2] = pv;
      }
      #pragma unroll
      for(int j=0;j<4;j++){
        uint4 v = rt[slot][j];
        float2 x0=cvt2(v.x), x1=cvt2(v.y), x2=cvt2(v.z), x3=cvt2(v.w);
        acc8[0]=fmaf(pvj[j],x0.x,acc8[0]); acc8[1]=fmaf(pvj[j],x0.y,acc8[1]);
        acc8[2]=fmaf(pvj[j],x1.x,acc8[2]); acc8[3]=fmaf(pvj[j],x1.y,acc8[3]);
        acc8[4]=fmaf(pvj[j],x2.x,acc8[4]); acc8[5]=fmaf(pvj[j],x2.y,acc8[5]);
        acc8[6]=fmaf(pvj[j],x3.x,acc8[6]); acc8[7]=fmaf(pvj[j],x3.y,acc8[7]);
      }
      mm = mnew;
      if(it + 4 < 32){
        #pragma unroll
        for(int j=0;j<4;j++)
          rt[slot][j] = *(const uint4*)(hxT +
              ((size_t)((it+4)*16 + 4*j + w)*BB + battn)*HH + lane*8);
      }
    }
    // cross-wave PV reduce + ctx store
    #pragma unroll
    for(int c=0;c<8;c+=4)
      *(float4*)&cp[w][lane*8+c] =
          make_float4(acc8[c],acc8[c+1],acc8[c+2],acc8[c+3]);
    __syncthreads();
    {
      int cc = 2*tid;
      float s0 = cp[0][cc]+cp[1][cc]+cp[2][cc]+cp[3][cc];
      float s1 = cp[0][cc+1]+cp[1][cc+1]+cp[2][cc+1]+cp[3][cc+1];
      float inv = 1.0f/l;
      union { u32 u; f16 h[2]; } pk;
      pk.h[0] = (f16)(s0*inv); pk.h[1] = (f16)(s1*inv);
      xst((u32*)(ctxg + (size_t)battn*HH + cc), pk.u);
    }
    post_flag(&fC[role], (u32)(t+1));
    wait_flags(fC, (u32)(t+1));

    { // stage ctx into cols 512..1023
      const u64* csrc = (const u64*)(ctxg + (size_t)b0*HH);
      #pragma unroll
      for(int i=0;i<16;i++){
        int e = i*256 + tid, row = e>>7, c8 = e&127;
        u64 vv = xld(csrc + (size_t)row*128 + c8);
        *(u64*)((row<16?stA:stB) + (row&15)*STRD + 512 + c8*4) = vv;
      }
    }
    __syncthreads();
    { // gates part2 (ctx half)
      const f16* arA = stA + m*STRD + q*8;
      const f16* arB = stB + m*STRD + q*8;
      #pragma unroll
      for(int kk=16;kk<32;kk++){
        f16x8 xa = *(const f16x8*)(arA + kk*32);
        f16x8 xb = *(const f16x8*)(arB + kk*32);
        aA = __builtin_amdgcn_mfma_f32_16x16x32_f16(xa, Bd[kk], aA, 0,0,0);
        aB = __builtin_amdgcn_mfma_f32_16x16x32_f16(xb, Bd[kk], aB, 0,0,0);
      }
    }
    #pragma unroll
    for(int r=0;r<4;r++){
      gtA[w*16+m][q*4+r] = aA[r];
      gtB[w*16+m][q*4+r] = aB[r];
    }
    __syncthreads();

    { // epilogue + fused output GEMV partial
      float (*gt)[18] = grp ? gtB : gtA;
      float gi0=gt[ec2][erow],    gi1=gt[ec2+1][erow];
      float gf0=gt[16+ec2][erow], gf1=gt[17+ec2][erow];
      float gg0=gt[32+ec2][erow], gg1=gt[33+ec2][erow];
      float go0=gt[48+ec2][erow], go1=gt[49+ec2][erow];
      float cv0 = sigm(gf0)*c0 + sigm(gi0)*tanh_f(gg0); c0 = cv0;
      float cv1 = sigm(gf1)*c1 + sigm(gi1)*tanh_f(gg1); c1 = cv1;
      float hv0 = sigm(go0)*tanh_f(cv0);
      float hv1 = sigm(go1)*tanh_f(cv1);
      union { u32 u; f16 h[2]; } pk;
      pk.h[0] = (f16)hv0; pk.h[1] = (f16)hv1;
      int b = b0 + grp*16 + erow;
      xst((u32*)(hdb + (size_t)b*HH + role*16 + ec2), pk.u);
      float po = hv0*ow0 + hv1*ow1;
      po += __shfl_xor(po, 1);
      po += __shfl_xor(po, 2);
      po += __shfl_xor(po, 4);
      if((tid & 7) == 0){
        float bias = (role == 0) ? ob0 : 0.f;
        atomicAdd(&out[(size_t)b*TT + t], po + bias);
      }
    }
    post_flag(&fH[role], (u32)(t+1));
  }
}

// ---------------------------------------------------------------------------
extern "C" void kernel_launch(void* const* d_in, const int* in_sizes, int n_in,
                              void* d_out, int out_size, void* d_ws, size_t ws_size,
                              hipStream_t stream){
  const float* enc_in = (const float*)d_in[0];
  const float* embW = (const float*)d_in[2];
  const float* embB = (const float*)d_in[3];
  const float* eWih = (const float*)d_in[4];
  const float* eWhh = (const float*)d_in[5];
  const float* ebih = (const float*)d_in[6];
  const float* ebhh = (const float*)d_in[7];
  const float* dWih = (const float*)d_in[8];
  const float* dWhh = (const float*)d_in[9];
  const float* dbih = (const float*)d_in[10];
  const float* dbhh = (const float*)d_in[11];
  const float* Wq   = (const float*)d_in[12];
  const float* bq   = (const float*)d_in[13];
  const float* Wk   = (const float*)d_in[14];
  // d_in[15]: bk — softmax-invariant, unused
  const float* outW = (const float*)d_in[16];
  const float* outb = (const float*)d_in[17];

  char* base = (char*)d_ws;
  f16* Wenc   = (f16*)(base + 0);            // 2,228,224
  f16* Wdec   = (f16*)(base + 2228224);      // 4,194,304
  f16* Wqf    = (f16*)(base + 6422528);      //   524,288
  f16* ctxg   = (f16*)(base + 6946816);      //   262,144
  f16* hdb    = (f16*)(base + 7208960);      //   262,144
  float* qtx  = (float*)(base + 7471104);    //   524,288
  float* Wqk_t= (float*)(base + 7995392);    // 1,048,576
  float* u    = (float*)(base + 9043968);    //     8,192
  float* v    = (float*)(base + 9052160);    //     8,192
  float* bd   = (float*)(base + 9060352);    //     8,192
  float* bqk  = (float*)(base + 9068544);    //     2,048
  u32* flags  = (u32*)(base + 9070592);      //     8,192 (8 pairs x 256 u32)
  f16* hxT    = (f16*)(base + 9437184);      // 134,217,728 [t][b][h]

  hipMemsetAsync(flags, 0, 8*256*sizeof(u32), stream);
  hipMemsetAsync(d_out, 0, (size_t)out_size*sizeof(float), stream);

  prep_uv  <<<8, 256, 0, stream>>>(eWih, embW, embB, ebih, ebhh, dbih, dbhh, u, v, bd);
  prep_bqk <<<2, 256, 0, stream>>>(bq, Wk, bqk);
  prep_wqk <<<512, 256, 0, stream>>>(Wq, Wk, Wqk_t);
  prep_wenc<<<dim3(128,17), 64, 0, stream>>>(eWhh, u, v, Wenc);
  prep_wdec<<<dim3(128,32), 64, 0, stream>>>(dWih, dWhh, Wdec);
  prep_wqfm<<<dim3(32,16),  64, 0, stream>>>(Wqk_t, Wqf);

  persist<<<256, 256, 0, stream>>>(enc_in, Wenc, Wdec, Wqf, bd, bqk,
                                   hxT, hdb, ctxg, qtx,
                                   outW, outb, (float*)d_out, flags);
}